// Round 8
// baseline (230.743 us; speedup 1.0000x reference)
//
#include <hip/hip_runtime.h>

#define NS 16
#define N_ATOMS 2000
#define NB 2000
#define NA 4000
#define NV 400000
#define NT 6000
#define NI 1000

#define OUT_S 819001
#define OFF_EB 0
#define OFF_EA 2000
#define OFF_EUB 6000
#define OFF_EV 6001
#define OFF_EC 406001
#define OFF_ET 806001
#define OFF_EI 812001
#define OFF_F 813001

#define CHARGE_TENTH 1.8222615f

#define NPAIRS 200000                  // NV/2
#define PPB 2048                       // pairs per scatter block
#define NCHUNKS ((NPAIRS + PPB - 1) / PPB)   // 98
#define BBLKS 4
#define NBOND_TOT (NB + NA + NT + NI)  // 13000
#define BTPB ((NBOND_TOT + BBLKS - 1) / BBLKS)  // 3250

typedef __fp16 h2 __attribute__((ext_vector_type(2)));

// ---------------------------------------------------------------------------
// Kernel 1: zero Force + E_ub; per-v params ws[v]; per-pair packed atom
// indices pairidx[p] (b0|b1<<16 for v0, same for v1).
__global__ __launch_bounds__(512) void prep_kernel(
    const float* __restrict__ v14,
    const float* __restrict__ q14,
    const float* __restrict__ pv,
    const float* __restrict__ pc,
    const int*   __restrict__ nb,
    const int*   __restrict__ nbi,
    float4* __restrict__ ws,
    uint2*  __restrict__ pairidx,
    float* __restrict__ out)
{
    int idx = blockIdx.x * blockDim.x + threadIdx.x;
    if (idx < NS)
        out[(size_t)idx * OUT_S + OFF_EUB] = 0.0f;
    if (idx < NS * N_ATOMS * 3) {
        int s = idx / (N_ATOMS * 3);
        int r = idx - s * (N_ATOMS * 3);
        out[(size_t)s * OUT_S + OFF_F + r] = 0.0f;
    }
    if (idx < NV) {
        int v = idx;
        int i = nb[v];
        int j = nb[NV + v];
        float2 pvi = ((const float2*)pv)[i];
        float2 pvj = ((const float2*)pv)[j];
        float sigma = pvi.x + pvj.x;
        float sig2  = sigma * sigma;
        float sig6  = sig2 * sig2 * sig2;
        float eps   = pvi.y * pvj.y * 0.01f * v14[v];
        float cc    = (CHARGE_TENTH * CHARGE_TENTH) * pc[i] * pc[j] * q14[v];
        float4 w;
        w.x = sig6; w.y = eps; w.z = cc; w.w = 0.0f;
        ws[v] = w;
    }
    if (idx < NPAIRS) {
        int4 aa = ((const int4*)nbi)[idx];   // {i0,j0,i1,j1} of v0=2p, v1=2p+1
        uint2 pk;
        pk.x = (unsigned)aa.x | ((unsigned)aa.y << 16);
        pk.y = (unsigned)aa.z | ((unsigned)aa.w << 16);
        pairidx[idx] = pk;
    }
}

// ---------------------------------------------------------------------------
// Kernel 2: pure streaming — energies + per-v force scalar fs. No scatter.
__global__ __launch_bounds__(256) void stream_kernel(
    const float*  __restrict__ lv,
    const float4* __restrict__ ws,
    float* __restrict__ fs,
    float* __restrict__ out)
{
    int v = blockIdx.x * 256 + threadIdx.x;
    int s = blockIdx.y;
    if (v >= NV) return;
    float4 w = ws[v];
    float r = lv[(size_t)s * NV + v];
    float rinv  = __builtin_amdgcn_rcpf(r);
    float r2inv = rinv * rinv;
    float r6inv = r2inv * r2inv * r2inv;
    float t     = w.x * r6inv;
    float eps   = w.y;
    float cc    = w.z;
    float* outE = out + (size_t)s * OUT_S;
    outE[OFF_EV + v] = eps * (t * t - 2.0f * t);
    outE[OFF_EC + v] = cc * rinv;
    fs[(size_t)s * NV + v] = 12.0f * eps * t * (1.0f - t) * rinv - cc * r2inv;
}

// ---------------------------------------------------------------------------
__device__ __forceinline__ void lds_pk_add(unsigned* base, int idx, float x, float y) {
    h2 ph = __builtin_amdgcn_cvt_pkrtz(x, y);
    unsigned pk = __builtin_bit_cast(unsigned, ph);
    unsigned addr = (unsigned)(uintptr_t)(&base[idx]);
    asm volatile("ds_pk_add_f16 %0, %1" : : "v"(addr), "v"(pk));
}

// ---------------------------------------------------------------------------
// Kernel 3: scatter only — fs * dlv accumulated into LDS, flushed via global
// atomics. Bonded terms on the extra blocks. DS-atomic count identical to R7.
__global__ __launch_bounds__(256, 4) void scatter_kernel(
    const float* __restrict__ fs,
    const uint2* __restrict__ pairidx,
    const float* __restrict__ dlv,
    const float* __restrict__ lb,
    const float* __restrict__ th,
    const float* __restrict__ sc,
    const float* __restrict__ c2i,
    const float* __restrict__ pb,
    const float* __restrict__ pa,
    const float* __restrict__ pt,
    const float* __restrict__ pim,
    const float* __restrict__ dlb,
    const float* __restrict__ dth,
    const float* __restrict__ dtt,
    const float* __restrict__ dc2,
    const int*   __restrict__ bidx,
    const int*   __restrict__ aidx,
    const int*   __restrict__ tidx,
    const int*   __restrict__ iidx,
    float* __restrict__ out)
{
    __shared__ unsigned fxy[N_ATOMS];
    __shared__ float    fz[N_ATOMS];
    int tid = threadIdx.x;
    int s   = blockIdx.x;
    int y   = blockIdx.y;
    float* outE = out + (size_t)s * OUT_S;
    float* F = outE + OFF_F;

    for (int k = tid; k < N_ATOMS; k += 256) { fxy[k] = 0u; fz[k] = 0.0f; }
    __syncthreads();

    if (y < NCHUNKS) {
        const int pbase = y * PPB;
        const float2* fsp = (const float2*)(fs + (size_t)s * NV);
        const float4* dfl = (const float4*)(dlv + (size_t)s * NV * 6);
        for (int it = 0; it < PPB / 256; ++it) {
            int praw = pbase + it * 256 + tid;
            bool live = praw < NPAIRS;
            int p = live ? praw : (NPAIRS - 1);
            float2 f2 = fsp[p];
            uint2  ii = pairidx[p];
            float4 A = dfl[3 * (size_t)p];
            float4 B = dfl[3 * (size_t)p + 1];
            float4 C = dfl[3 * (size_t)p + 2];
            float f0 = live ? f2.x : 0.0f;
            float f1 = live ? f2.y : 0.0f;
            int b0 = (int)(ii.x & 0xffffu), b1 = (int)(ii.x >> 16);
            int b2 = (int)(ii.y & 0xffffu), b3 = (int)(ii.y >> 16);
            lds_pk_add(fxy, b0, A.x * f0, A.y * f0);
            atomicAdd(&fz[b0], A.z * f0);
            lds_pk_add(fxy, b1, A.w * f0, B.x * f0);
            atomicAdd(&fz[b1], B.y * f0);
            lds_pk_add(fxy, b2, B.z * f1, B.w * f1);
            atomicAdd(&fz[b2], C.x * f1);
            lds_pk_add(fxy, b3, C.y * f1, C.z * f1);
            atomicAdd(&fz[b3], C.w * f1);
        }
    } else {
        int t0 = (y - NCHUNKS) * BTPB;
        int tend = t0 + BTPB; if (tend > NBOND_TOT) tend = NBOND_TOT;
        for (int t = t0 + tid; t < tend; t += 256) {
            if (t < NB) {
                int b = t;
                float2 p = ((const float2*)pb)[b];
                float K  = p.x * 100.0f;
                float d  = lb[s * NB + b] - p.y;
                outE[OFF_EB + b] = K * d * d;
                float g = 2.0f * K * d;
                const float2* dd = (const float2*)(dlb + ((size_t)s * NB + b) * 6);
                float2 d0 = dd[0], d1 = dd[1], d2 = dd[2];
                int a0 = bidx[2 * b], a1 = bidx[2 * b + 1];
                lds_pk_add(fxy, a0, d0.x * g, d0.y * g);
                atomicAdd(&fz[a0], d1.x * g);
                lds_pk_add(fxy, a1, d1.y * g, d2.x * g);
                atomicAdd(&fz[a1], d2.y * g);
            } else if (t < NB + NA) {
                int a = t - NB;
                float2 p = ((const float2*)pa)[a];
                float Ka  = p.x * 10.0f;
                float da  = th[s * NA + a] - p.y * 0.31415926535f;
                outE[OFF_EA + a] = Ka * da * da;
                float g = 2.0f * Ka * da;
                const float* dd = dth + ((size_t)s * NA + a) * 9;
                int a0 = aidx[3 * a], a1 = aidx[3 * a + 1], a2 = aidx[3 * a + 2];
                lds_pk_add(fxy, a0, dd[0] * g, dd[1] * g);
                atomicAdd(&fz[a0], dd[2] * g);
                lds_pk_add(fxy, a1, dd[3] * g, dd[4] * g);
                atomicAdd(&fz[a1], dd[5] * g);
                lds_pk_add(fxy, a2, dd[6] * g, dd[7] * g);
                atomicAdd(&fz[a2], dd[8] * g);
            } else if (t < NB + NA + NT) {
                int tt = t - (NB + NA);
                const float4* s8 = (const float4*)(sc + ((size_t)s * NT + tt) * 8);
                float4 sA = s8[0], sB = s8[1];
                float4 p4 = ((const float4*)pt)[tt];
                float E  = sA.y * p4.x + sA.w * p4.y + sB.y * p4.z + sB.w * p4.w;
                float Sf = sA.x * p4.x + sA.z * p4.y * 2.0f + sB.x * p4.z * 3.0f + sB.z * p4.w * 4.0f;
                outE[OFF_ET + tt] = E;
                float g = -Sf;
                const float4* dd = (const float4*)(dtt + ((size_t)s * NT + tt) * 12);
                float4 dA = dd[0], dB = dd[1], dC = dd[2];
                int a0 = tidx[4 * tt], a1 = tidx[4 * tt + 1],
                    a2 = tidx[4 * tt + 2], a3 = tidx[4 * tt + 3];
                lds_pk_add(fxy, a0, dA.x * g, dA.y * g);
                atomicAdd(&fz[a0], dA.z * g);
                lds_pk_add(fxy, a1, dA.w * g, dB.x * g);
                atomicAdd(&fz[a1], dB.y * g);
                lds_pk_add(fxy, a2, dB.z * g, dB.w * g);
                atomicAdd(&fz[a2], dC.x * g);
                lds_pk_add(fxy, a3, dC.y * g, dC.z * g);
                atomicAdd(&fz[a3], dC.w * g);
            } else {
                int ii = t - (NB + NA + NT);
                float ki = pim[ii];
                outE[OFF_EI + ii] = ki * (1.0f - c2i[s * NI + ii]);
                float g = -ki;
                const float4* dd = (const float4*)(dc2 + ((size_t)s * NI + ii) * 12);
                float4 dA = dd[0], dB = dd[1], dC = dd[2];
                int a0 = iidx[4 * ii], a1 = iidx[4 * ii + 1],
                    a2 = iidx[4 * ii + 2], a3 = iidx[4 * ii + 3];
                lds_pk_add(fxy, a0, dA.x * g, dA.y * g);
                atomicAdd(&fz[a0], dA.z * g);
                lds_pk_add(fxy, a1, dA.w * g, dB.x * g);
                atomicAdd(&fz[a1], dB.y * g);
                lds_pk_add(fxy, a2, dB.z * g, dB.w * g);
                atomicAdd(&fz[a2], dC.x * g);
                lds_pk_add(fxy, a3, dC.y * g, dC.z * g);
                atomicAdd(&fz[a3], dC.w * g);
            }
        }
    }

    asm volatile("s_waitcnt lgkmcnt(0)" ::: "memory");
    __syncthreads();

    for (int k = tid; k < N_ATOMS; k += 256) {
        unsigned u = fxy[k];
        h2 hv = __builtin_bit_cast(h2, u);
        float x  = (float)hv.x;
        float yv = (float)hv.y;
        float z  = fz[k];
        if (x  != 0.0f) atomicAdd(&F[3 * k + 0], x);
        if (yv != 0.0f) atomicAdd(&F[3 * k + 1], yv);
        if (z  != 0.0f) atomicAdd(&F[3 * k + 2], z);
    }
}

// ---------------------------------------------------------------------------
extern "C" void kernel_launch(void* const* d_in, const int* in_sizes, int n_in,
                              void* d_out, int out_size, void* d_ws, size_t ws_size,
                              hipStream_t stream) {
    const float* lb  = (const float*)d_in[0];
    const float* th  = (const float*)d_in[1];
    const float* lv  = (const float*)d_in[2];
    const float* sc  = (const float*)d_in[3];
    const float* c2i = (const float*)d_in[4];
    const float* v14 = (const float*)d_in[5];
    const float* q14 = (const float*)d_in[6];
    const float* pb  = (const float*)d_in[7];
    const float* pa  = (const float*)d_in[8];
    const float* pv  = (const float*)d_in[9];
    const float* pc  = (const float*)d_in[10];
    const float* pt  = (const float*)d_in[11];
    const float* pim = (const float*)d_in[12];
    const float* dlb = (const float*)d_in[13];
    const float* dth = (const float*)d_in[14];
    const float* dlv = (const float*)d_in[15];
    const float* dtt = (const float*)d_in[16];
    const float* dc2 = (const float*)d_in[17];
    const int* nb    = (const int*)d_in[18];
    const int* bidx  = (const int*)d_in[19];
    const int* aidx  = (const int*)d_in[20];
    const int* nbi   = (const int*)d_in[21];
    const int* tidx  = (const int*)d_in[22];
    const int* iidx  = (const int*)d_in[23];
    float* out = (float*)d_out;

    // ws layout: ws params (NV float4) | pairidx (NPAIRS uint2) | fs (NS*NV f32)
    float4* ws      = (float4*)d_ws;
    uint2*  pairidx = (uint2*)((float*)d_ws + (size_t)NV * 4);
    float*  fs      = (float*)d_ws + (size_t)NV * 4 + (size_t)NPAIRS * 2;

    // 1) prep
    prep_kernel<<<(NV + 511) / 512, 512, 0, stream>>>(
        v14, q14, pv, pc, nb, nbi, ws, pairidx, out);

    // 2) pure streaming: energies + fs
    {
        dim3 grid((NV + 255) / 256, NS);
        stream_kernel<<<grid, 256, 0, stream>>>(lv, ws, fs, out);
    }

    // 3) scatter + bonded
    {
        dim3 grid(NS, NCHUNKS + BBLKS);
        scatter_kernel<<<grid, 256, 0, stream>>>(
            fs, pairidx, dlv, lb, th, sc, c2i, pb, pa, pt, pim,
            dlb, dth, dtt, dc2, bidx, aidx, tidx, iidx, out);
    }
}